// Round 5
// baseline (124.427 us; speedup 1.0000x reference)
//
#include <hip/hip_runtime.h>
#include <hip/hip_bf16.h>

typedef unsigned short u16;
typedef float f32x4 __attribute__((ext_vector_type(4)));
typedef __bf16 bf16x8 __attribute__((ext_vector_type(8)));

#define M_DIM 16384
#define IN_DIM 1024
#define OUT_DIM 1024
#define K_KNOTS 12
#define KCAT 2048   // concatenated K dimension

// ---- helpers ----
__device__ __forceinline__ u16 f2bf(float f) {
    unsigned int u = __builtin_bit_cast(unsigned int, f);
    u = u + 0x7FFFu + ((u >> 16) & 1u);   // RNE
    return (u16)(u >> 16);
}

__device__ __forceinline__ void gload_lds16(const void* g, void* l) {
    __builtin_amdgcn_global_load_lds(
        (const __attribute__((address_space(1))) unsigned int*)g,
        (__attribute__((address_space(3))) unsigned int*)l, 16, 0, 0);
}

// ---- kernel 1: per-feature knot prep (sort + sigmoid mask) ----
__global__ void prep_kernel(const float* __restrict__ grid,
                            const float* __restrict__ coeffs,
                            const float* __restrict__ alive,
                            float* __restrict__ pmc,     // [IN][12]
                            float* __restrict__ pgmin,   // [IN]
                            float* __restrict__ pscale)  // [IN]
{
    int i = blockIdx.x * blockDim.x + threadIdx.x;
    if (i >= IN_DIM) return;
    float g[K_KNOTS], c[K_KNOTS], a[K_KNOTS];
    for (int k = 0; k < K_KNOTS; ++k) {
        g[k] = grid[i * K_KNOTS + k];
        c[k] = coeffs[i * K_KNOTS + k];
        a[k] = alive[i * K_KNOTS + k];
    }
    for (int k = 1; k < K_KNOTS; ++k) {
        float gk = g[k], ck = c[k], ak = a[k];
        int j = k - 1;
        while (j >= 0 && g[j] > gk) {
            g[j + 1] = g[j]; c[j + 1] = c[j]; a[j + 1] = a[j]; --j;
        }
        g[j + 1] = gk; c[j + 1] = ck; a[j + 1] = ak;
    }
    for (int k = 0; k < K_KNOTS; ++k)
        pmc[i * K_KNOTS + k] = c[k] / (1.0f + expf(-a[k]));
    pgmin[i] = g[0];
    pscale[i] = (float)(K_KNOTS - 1) / fmaxf(g[K_KNOTS - 1] - g[0], 1e-6f);
}

// ---- kernel 2: pack [proj_w | res_w] into bf16 B^T (OUT x KCAT) ----
__global__ __launch_bounds__(256) void conv_w_kernel(
    const float* __restrict__ pw, const float* __restrict__ rw,
    u16* __restrict__ Bw)
{
    long t = (long)blockIdx.x * blockDim.x + threadIdx.x;
    long nquad = (long)OUT_DIM * KCAT / 4;
    if (t >= nquad) return;
    long o = t / (KCAT / 4);
    int j = (int)(t % (KCAT / 4)) * 4;
    const float* src = (j < IN_DIM) ? &pw[o * IN_DIM + j] : &rw[o * IN_DIM + (j - IN_DIM)];
    float4 v = *(const float4*)src;
    ushort4 u;
    u.x = f2bf(v.x); u.y = f2bf(v.y); u.z = f2bf(v.z); u.w = f2bf(v.w);
    *(ushort4*)&Bw[o * KCAT + j] = u;
}

// ---- kernel 3: build A = [spline(x) | x] in bf16 (M x 2048) ----
__global__ __launch_bounds__(256) void build_a_kernel(
    const float* __restrict__ x,
    const float* __restrict__ pmc,
    const float* __restrict__ pgmin,
    const float* __restrict__ pscale,
    u16* __restrict__ Abf)
{
    __shared__ float s_mc[IN_DIM * K_KNOTS];
    __shared__ float s_gmin[IN_DIM];
    __shared__ float s_scale[IN_DIM];
    int tid = threadIdx.x;
    for (int i = tid; i < IN_DIM * K_KNOTS; i += 256) s_mc[i] = pmc[i];
    for (int i = tid; i < IN_DIM; i += 256) { s_gmin[i] = pgmin[i]; s_scale[i] = pscale[i]; }
    __syncthreads();

    for (int r = 0; r < M_DIM / 1024; ++r) {
        int m = blockIdx.x + r * 1024;
        float4 xv = *(const float4*)&x[(long)m * IN_DIM + tid * 4];
        float xs[4] = {xv.x, xv.y, xv.z, xv.w};
        ushort4 sp_out, x_out;
        u16* spp = &sp_out.x;
        u16* xpp = &x_out.x;
        #pragma unroll
        for (int j = 0; j < 4; ++j) {
            int i = tid * 4 + j;
            float xx = xs[j];
            float xn = (xx - s_gmin[i]) * s_scale[i];
            xn = fminf(fmaxf(xn, 0.0f), (float)(K_KNOTS - 1));
            int l = (int)xn;
            if (l > K_KNOTS - 2) l = K_KNOTS - 2;
            float frac = xn - (float)l;
            float cl = s_mc[i * K_KNOTS + l];
            float cr = s_mc[i * K_KNOTS + l + 1];
            float spv = cl + frac * (cr - cl);
            spp[j] = f2bf(spv);
            xpp[j] = f2bf(xx);
        }
        *(ushort4*)&Abf[(long)m * KCAT + tid * 4] = sp_out;
        *(ushort4*)&Abf[(long)m * KCAT + IN_DIM + tid * 4] = x_out;
    }
}

// ---- kernel 4: 256x256 bf16 GEMM, m201-style 8-phase / 2-K-tile schedule ----
// 8 waves (2M x 4N), BK=64 (kk=0/1), double-buffered LDS (128 KiB, buf0=even
// tile, buf1=odd tile), lane-ordered conflict-free frags, per-phase:
// {4-8 ds_read -> stage 1 unit -> [vmcnt(6) @Ph4/8] -> barrier -> lgkm(0) ->
//  setprio(1) 16 MFMA setprio(0) -> barrier}.
#define TBK 64
#define NT (KCAT / TBK)   // 32 K-tiles, 16 iterations

#define BAR()     asm volatile("s_barrier" ::: "memory")
#define VM6BAR()  asm volatile("s_waitcnt vmcnt(6)\ns_barrier" ::: "memory")
#define LGKM0()   do { asm volatile("s_waitcnt lgkmcnt(0)" ::: "memory"); \
                       __builtin_amdgcn_sched_barrier(0); } while (0)

#define READ_A(buf, kk, mh) \
    _Pragma("unroll") \
    for (int m_ = 0; m_ < 4; ++m_) \
        af[m_] = *(const bf16x8*)&lds[(buf) + (kk)*8192 + (wm*8 + (mh)*4 + m_)*512 + loff];

#define READ_B(buf, kk) \
    _Pragma("unroll") \
    for (int n_ = 0; n_ < 4; ++n_) \
        bfr[n_] = *(const bf16x8*)&lds[32768 + (buf) + (kk)*8192 + (wn*4 + n_)*512 + loff];

#define MFMA16(base) \
    __builtin_amdgcn_s_setprio(1); \
    _Pragma("unroll") \
    for (int m_ = 0; m_ < 4; ++m_) \
        _Pragma("unroll") \
        for (int n_ = 0; n_ < 4; ++n_) \
            acc[(base) + m_][n_] = __builtin_amdgcn_mfma_f32_16x16x32_bf16( \
                af[m_], bfr[n_], acc[(base) + m_][n_], 0, 0, 0); \
    __builtin_amdgcn_s_setprio(0);

#define STAGE_A(koff, kk, buf) do { \
    gload_lds16(pA0 + (koff) + (kk)*32, &lds[(buf) + (kk)*8192 + d0]); \
    gload_lds16(pA1 + (koff) + (kk)*32, &lds[(buf) + (kk)*8192 + d1]); } while (0)
#define STAGE_B(koff, kk, buf) do { \
    gload_lds16(pB0 + (koff) + (kk)*32, &lds[32768 + (buf) + (kk)*8192 + d0]); \
    gload_lds16(pB1 + (koff) + (kk)*32, &lds[32768 + (buf) + (kk)*8192 + d1]); } while (0)

__global__ __launch_bounds__(512, 2) void gemm_kernel(
    const u16* __restrict__ A,   // M x KCAT
    const u16* __restrict__ B,   // N x KCAT (B^T layout)
    const float* __restrict__ bias,
    float* __restrict__ C)
{
    // LDS element map (u16 units): A buf0 @0, A buf1 @16384; B buf0 @32768,
    // B buf1 @49152. unit kk: +kk*8192 ; frag f: +f*512 ; lane l: elem l*8.
    __shared__ __align__(16) u16 lds[65536];   // 128 KiB

    const int tid  = threadIdx.x;
    const int lane = tid & 63;
    const int wave = tid >> 6;
    const int wm   = wave >> 2;   // 0..1
    const int wn   = wave & 3;    // 0..3

    // bijective XCD swizzle (nwg = 256)
    int wgid = (blockIdx.x & 7) * 32 + (blockIdx.x >> 3);
    const int brow = (wgid >> 2) * 256;
    const int bcol = (wgid & 3) * 256;

    // staging decode: q = pass*512 + tid
    // global row = base + (q>>6)*16 + (q&15) ; col = ((q>>4)&3)*8 (+kk*32 +k0)
    const int q0 = tid, q1 = 512 + tid;
    const int r0 = (q0 >> 6) * 16 + (q0 & 15), c0 = ((q0 >> 4) & 3) * 8;
    const int r1 = (q1 >> 6) * 16 + (q1 & 15), c1 = ((q1 >> 4) & 3) * 8;
    const u16* pA0 = A + (long)(brow + r0) * KCAT + c0;
    const u16* pA1 = A + (long)(brow + r1) * KCAT + c1;
    const u16* pB0 = B + (long)(bcol + r0) * KCAT + c0;
    const u16* pB1 = B + (long)(bcol + r1) * KCAT + c1;

    const int d0 = tid * 8;          // pass-0 LDS dest (elems) within unit
    const int d1 = 4096 + tid * 8;   // pass-1
    const int loff = lane * 8;       // lane-order frag read

    f32x4 acc[8][4] = {};
    bf16x8 af[4], bfr[4];

    // prologue: queue order A0(0),B0(0),A1(0),B1(0),B0(1),A0(1),B1(1)
    STAGE_A(0,   0, 0);
    STAGE_B(0,   0, 0);
    STAGE_A(0,   1, 0);
    STAGE_B(0,   1, 0);
    STAGE_B(TBK, 0, 16384);
    STAGE_A(TBK, 0, 16384);
    STAGE_B(TBK, 1, 16384);
    VM6BAR();   // tile-0 units complete; {B0,A0,B1}(1) may remain in flight

    #pragma unroll 1
    for (int t = 0; t < NT / 2; ++t) {
        const int T   = 2 * t;
        const int kp1 = (T + 1) * TBK;
        const int kp2 = (T + 2 < NT) ? (T + 2) * TBK : 0;  // wrap: staged, never read
        const int kp3 = (T + 3 < NT) ? (T + 3) * TBK : 0;

        // ---- Ph1: tile T (buf0) mh0 kk0 ; stage A1(T+1) ----
        READ_A(0, 0, 0); READ_B(0, 0);
        STAGE_A(kp1, 1, 16384);
        BAR(); LGKM0();
        MFMA16(0);
        BAR();

        // ---- Ph2: tile T mh1 kk0 ; stage B0(T+2) ----
        READ_A(0, 0, 1);
        STAGE_B(kp2, 0, 0);
        BAR(); LGKM0();
        MFMA16(4);
        BAR();

        // ---- Ph3: tile T mh0 kk1 ; stage A0(T+2) ----
        READ_A(0, 1, 0); READ_B(0, 1);
        STAGE_A(kp2, 0, 0);
        BAR(); LGKM0();
        MFMA16(0);
        BAR();

        // ---- Ph4: tile T mh1 kk1 ; stage B1(T+2) ; vmcnt publishes tile T+1 ----
        READ_A(0, 1, 1);
        STAGE_B(kp2, 1, 0);
        VM6BAR(); LGKM0();
        MFMA16(4);
        BAR();

        // ---- Ph5: tile T+1 (buf1) mh0 kk0 ; stage A1(T+2) ----
        READ_A(16384, 0, 0); READ_B(16384, 0);
        STAGE_A(kp2, 1, 0);
        BAR(); LGKM0();
        MFMA16(0);
        BAR();

        // ---- Ph6: tile T+1 mh1 kk0 ; stage B0(T+3) ----
        READ_A(16384, 0, 1);
        STAGE_B(kp3, 0, 16384);
        BAR(); LGKM0();
        MFMA16(4);
        BAR();

        // ---- Ph7: tile T+1 mh0 kk1 ; stage A0(T+3) ----
        READ_A(16384, 1, 0); READ_B(16384, 1);
        STAGE_A(kp3, 0, 16384);
        BAR(); LGKM0();
        MFMA16(0);
        BAR();

        // ---- Ph8: tile T+1 mh1 kk1 ; stage B1(T+3) ; vmcnt publishes tile T+2 ----
        READ_A(16384, 1, 1);
        STAGE_B(kp3, 1, 16384);
        VM6BAR(); LGKM0();
        MFMA16(4);
        BAR();
    }

    // ---- epilogue ----
    const int crow0 = brow + wm * 128 + (lane >> 4) * 4;
    const int ccol0 = bcol + wn * 64 + (lane & 15);
    float bv[4];
    #pragma unroll
    for (int n = 0; n < 4; ++n) bv[n] = bias[ccol0 + n * 16];
    #pragma unroll
    for (int m = 0; m < 8; ++m) {
        #pragma unroll
        for (int n = 0; n < 4; ++n) {
            #pragma unroll
            for (int j = 0; j < 4; ++j) {
                int row = crow0 + m * 16 + j;
                C[(long)row * OUT_DIM + ccol0 + n * 16] = acc[m][n][j] + bv[n];
            }
        }
    }
}

extern "C" void kernel_launch(void* const* d_in, const int* in_sizes, int n_in,
                              void* d_out, int out_size, void* d_ws, size_t ws_size,
                              hipStream_t stream) {
    const float* x      = (const float*)d_in[0];
    const float* grid   = (const float*)d_in[1];
    const float* coeffs = (const float*)d_in[2];
    const float* alive  = (const float*)d_in[3];
    const float* proj_w = (const float*)d_in[4];
    const float* proj_b = (const float*)d_in[5];
    const float* res_w  = (const float*)d_in[6];
    float* out = (float*)d_out;

    char* w = (char*)d_ws;
    size_t a_bytes = (size_t)M_DIM * KCAT * sizeof(u16);     // 64 MiB
    size_t b_bytes = (size_t)OUT_DIM * KCAT * sizeof(u16);   // 4 MiB
    u16* Abf   = (u16*)w;
    u16* Bw    = (u16*)(w + a_bytes);
    float* pmc = (float*)(w + a_bytes + b_bytes);
    float* pgmin  = pmc + IN_DIM * K_KNOTS;
    float* pscale = pgmin + IN_DIM;

    prep_kernel<<<(IN_DIM + 255) / 256, 256, 0, stream>>>(grid, coeffs, alive,
                                                          pmc, pgmin, pscale);
    conv_w_kernel<<<(OUT_DIM * KCAT / 4 + 255) / 256, 256, 0, stream>>>(proj_w, res_w, Bw);
    build_a_kernel<<<1024, 256, 0, stream>>>(x, pmc, pgmin, pscale, Abf);
    gemm_kernel<<<(M_DIM / 256) * (OUT_DIM / 256), 512, 0, stream>>>(Abf, Bw, proj_b, out);
}